// Round 15
// baseline (104.422 us; speedup 1.0000x reference)
//
#include <hip/hip_runtime.h>

// corr via MFMA band extraction + LDS-transposed coalesced stores.
// out[b,di*9+(dj+4),h,w] = sum_c x[b,c,h,w] * y[b,c,refl(h+di-4),refl(w+dj)]
// A = Y_bf16[w'-tile, c], B = X_bf16[c, w-tile]; D[w',w] diagonals = dj.
// R15: 5 resident blocks/CU (HT=8, grid 2048, LDS exactly 32768B: YRING=9,
// PRS=64, didx80 direct) + 2-deep load pipeline (loads issued a full
// iteration before their LDS write / convert).

#define HH   256
#define WW   256
#define CCH  64
#define KRAD 4
#define ND   81

#define WT   16
#define HT   8
#define WY   24
#define RSTRIDE 128             // 64c*2B, XOR-swizzled 16B chunks
#define YRING 9
#define YSLOT (WY * RSTRIDE)    // 3072 B
#define PRS   64                // pstage row = exactly 16 floats
#define PROWS 80                // didx 0..79 staged; didx 80 stored direct
#define PSLOT (PROWS * PRS)     // 5120 B

typedef __attribute__((ext_vector_type(8))) short bf16x8;
typedef __attribute__((ext_vector_type(4))) float f32x4;

__device__ __forceinline__ int reflect(int v, int n) {
    v = v < 0 ? -v : v;
    return v >= n ? 2 * n - 2 - v : v;
}
__device__ __forceinline__ unsigned f2bf_pk(float a, float b) {
    union { float f; unsigned u; } xa, xb;
    xa.f = a; xb.f = b;
    unsigned ra = (xa.u + 0x7fffu + ((xa.u >> 16) & 1u)) >> 16;
    unsigned rb = (xb.u + 0x7fffu + ((xb.u >> 16) & 1u)) >> 16;
    return ra | (rb << 16);
}
__device__ __forceinline__ int mod9(int s) {    // s in [0, 18)
    return s >= 9 ? s - 9 : s;
}

__global__ __launch_bounds__(256, 5) void corr_mfma_kernel(
    const float* __restrict__ x, const float* __restrict__ y,
    float* __restrict__ out)
{
    __shared__ char lds[YRING * YSLOT + PSLOT];   // 27648 + 5120 = 32768 B exactly
    char* ylds   = lds;
    char* pstage = lds + YRING * YSLOT;

    // XCD-chunked bijective swizzle: 2048 blocks = 8 XCDs * 256
    const int d  = blockIdx.x;
    const int v  = (d & 7) * 256 + (d >> 3);
    const int bx = v & 15;
    const int by = (v >> 4) & 31;
    const int b  = v >> 9;
    const int w0 = bx * WT;
    const int h0 = by * HT;

    const int t    = threadIdx.x;
    const int wid  = t >> 6;
    const int lane = t & 63;
    const int lq   = lane >> 4;      // 0..3
    const int ln   = lane & 15;      // 0..15

    const size_t plane = (size_t)HH * WW;
    const float* yb = y + (size_t)b * CCH * plane;
    const float* xb = x + (size_t)b * CCH * plane;
    float* outb = out + (size_t)b * ND * plane;

    // staging lane mapping for Y rows
    const int yp  = t & 31;          // w' position, active < WY
    const int ycg = t >> 5;          // c group: c = 8*ycg + j

    auto loadY = [&](int L, float* v8) {         // L: local row (global h = h0-4+L)
        int gh = reflect(h0 - KRAD + L, HH);
        int pc = yp < WY ? yp : WY - 1;
        int gw = reflect(w0 - KRAD + pc, WW);
        const float* src = yb + (size_t)(ycg * 8) * plane + (size_t)gh * WW + gw;
#pragma unroll
        for (int j = 0; j < 8; ++j) v8[j] = src[(size_t)j * plane];
    };
    auto writeY = [&](int L, const float* v8) {
        if (yp < WY) {
            char* dst = ylds + mod9(L) * YSLOT + yp * RSTRIDE
                      + (((unsigned)(ycg * 16)) ^ ((unsigned)(yp & 7) << 4));
            union { unsigned u[4]; uint4 q; } pk;
#pragma unroll
            for (int m = 0; m < 4; ++m)
                pk.u[m] = f2bf_pk(v8[2 * m], v8[2 * m + 1]);
            *(uint4*)dst = pk.q;
        }
    };
    // X direct-to-register: lane (lq,ln) holds B[c = lq*8+j (+32), w0+ln]
    auto loadX = [&](int hrow, float* v16) {
        int gh = reflect(hrow, HH);
        const float* src = xb + (size_t)(lq * 8) * plane + (size_t)gh * WW + (w0 + ln);
#pragma unroll
        for (int j = 0; j < 8; ++j) v16[j] = src[(size_t)j * plane];
        const float* src2 = src + (size_t)32 * plane;
#pragma unroll
        for (int j = 0; j < 8; ++j) v16[8 + j] = src2[(size_t)j * plane];
    };
    auto xconv = [&](const float* v16, bf16x8& f0, bf16x8& f1) {
        union { unsigned u[4]; bf16x8 v; } c0, c1;
#pragma unroll
        for (int m = 0; m < 4; ++m) {
            c0.u[m] = f2bf_pk(v16[2 * m], v16[2 * m + 1]);
            c1.u[m] = f2bf_pk(v16[8 + 2 * m], v16[9 + 2 * m]);
        }
        f0 = c0.v; f1 = c1.v;
    };

    const int mbase = lq * 4;
    const int prow  = t >> 4;        // readback: didx sub-row
    const int pcol  = t & 15;        // readback: w column
    const unsigned swl = ((unsigned)(ln & 7)) << 4;

    // one iteration body (hh, frags bf0/bf1, write-data yW)
    auto body = [&](int hh, const bf16x8& bf0, const bf16x8& bf1, const float* yW) {
        const int h = h0 + hh;

        // compute: 18 (di,wt) units split 5/5/4/4 across waves
        for (int u = wid; u < 18; u += 4) {
            const int di = u >> 1;
            const int wt = u & 1;
            const int slot = mod9(hh + di);
            const char* abase = ylds + slot * YSLOT + (wt * 16 + ln) * RSTRIDE;
            bf16x8 af0 = *(const bf16x8*)(abase + (((unsigned)(lq * 16)) ^ swl));
            bf16x8 af1 = *(const bf16x8*)(abase + (((unsigned)(64 + lq * 16)) ^ swl));
            f32x4 dacc = {0.f, 0.f, 0.f, 0.f};
            dacc = __builtin_amdgcn_mfma_f32_16x16x32_bf16(af0, bf0, dacc, 0, 0, 0);
            dacc = __builtin_amdgcn_mfma_f32_16x16x32_bf16(af1, bf1, dacc, 0, 0, 0);
#pragma unroll
            for (int r = 0; r < 4; ++r) {
                const int vr = mbase + r - ln + (wt ? 16 : 0);   // dj+4
                if ((unsigned)vr <= 8u) {
                    const int didx = di * 9 + vr;
                    if (didx < PROWS)
                        *(float*)(pstage + didx * PRS + ln * 4) = dacc[r];
                    else   // didx == 80: one coalesced 16-lane line, direct
                        outb[(size_t)80 * plane + (size_t)h * WW + (w0 + ln)] = dacc[r];
                }
            }
        }

        // barrier 1: pstage writes visible + ring/frag reads drained
        __builtin_amdgcn_sched_barrier(0);
        asm volatile("s_waitcnt lgkmcnt(0)" ::: "memory");
        __builtin_amdgcn_s_barrier();
        __builtin_amdgcn_sched_barrier(0);

        // stage ring row hh+9 (slot of retired row hh); data loaded last iter
        if (hh < HT - 1) writeY(hh + 9, yW);

        // coalesced readback: didx 0..79 x 16 w (full 64B lines)
        {
            float* og = outb + (size_t)h * WW + (w0 + pcol);
#pragma unroll
            for (int p = 0; p < 5; ++p) {
                const int didx = p * 16 + prow;
                float vv = *(const float*)(pstage + didx * PRS + pcol * 4);
                og[(size_t)didx * plane] = vv;
            }
        }

        // barrier 2: readback + ring write complete before next iter
        __builtin_amdgcn_sched_barrier(0);
        asm volatile("s_waitcnt lgkmcnt(0)" ::: "memory");
        __builtin_amdgcn_s_barrier();
        __builtin_amdgcn_sched_barrier(0);
    };

    float yA[8], yB[8], xvE[16], xvO[16];
    bf16x8 bf0, bf1;

    // ---- prologue: ring rows L=0..8 (2-deep pipelined); pipeline seeds ----
    loadY(0, yA);
#pragma unroll 1
    for (int j = 0; j < 9; ++j) {
        if (j < 8) loadY(j + 1, yB);
        writeY(j, yA);
#pragma unroll
        for (int m = 0; m < 8; ++m) yA[m] = yB[m];
    }
    loadY(9, yA);        // write-data for iter 0
    loadX(h0, xvE);      // frags for iter 0
    loadX(h0 + 1, xvO);  // frags for iter 1
    __syncthreads();

    // ---- main loop: HT rows, x2 unrolled for static ping-pong ----
#pragma unroll 1
    for (int e = 0; e < HT / 2; ++e) {
        const int hh0 = 2 * e;

        // even iter: convert xvE, reload into xvE for row h+2; load yB for L=hh0+10
        xconv(xvE, bf0, bf1);
        if (hh0 < HT - 2) {
            loadY(hh0 + 10, yB);
            loadX(h0 + hh0 + 2, xvE);
        }
        body(hh0, bf0, bf1, yA);

        // odd iter: convert xvO, reload into xvO; load yA for L=hh0+11
        xconv(xvO, bf0, bf1);
        if (hh0 + 1 < HT - 2) {
            loadY(hh0 + 11, yA);
            loadX(h0 + hh0 + 3, xvO);
        }
        body(hh0 + 1, bf0, bf1, yB);
    }
}

extern "C" void kernel_launch(void* const* d_in, const int* in_sizes, int n_in,
                              void* d_out, int out_size, void* d_ws, size_t ws_size,
                              hipStream_t stream) {
    const float* x = (const float*)d_in[0];
    const float* y = (const float*)d_in[1];
    float* out = (float*)d_out;

    dim3 grid(2048);   // 16 w-tiles * 32 h-tiles * 4 batch, XCD-swizzled in-kernel
    dim3 block(256);
    corr_mfma_kernel<<<grid, block, 0, stream>>>(x, y, out);
}